// Round 3
// baseline (366.893 us; speedup 1.0000x reference)
//
#include <hip/hip_runtime.h>
#include <hip/hip_bf16.h>
#include <math.h>

#define T_LEN 4096
#define BATCH 16

// ---------------------------------------------------------------------------
// k_gcn: adapter + node projections + A_HAT propagation + relu + node-mean.
// (unchanged from R8)
// ---------------------------------------------------------------------------
__global__ __launch_bounds__(256) void k_gcn(
    const float* __restrict__ x,      // [B][T][218]
    const float* __restrict__ gcn_w,  // [18][64]
    float* __restrict__ hp)           // [B][64][T]
{
    __shared__ float xt[218 * 36];
    __shared__ float wg[18 * 64];

    const int b   = blockIdx.y;
    const int t0  = blockIdx.x * 32;
    const int tid = threadIdx.x;

    const float* xb = x + ((long)b * T_LEN + t0) * 218;
    #pragma unroll 1
    for (int i = tid; i < 32 * 218; i += 256) {
        const int t = i / 218;
        const int c = i - 218 * t;
        xt[c * 36 + t] = xb[i];
    }
    for (int i = tid; i < 18 * 64; i += 256) wg[i] = gcn_w[i];
    __syncthreads();

    const int dg = tid >> 4;
    const int tt = tid & 15;
    const int d0 = dg * 4;
    const int tb = tt * 2;

    float wr[10][4];
    #pragma unroll
    for (int c = 0; c < 10; ++c)
        *(float4*)wr[c] = *(const float4*)(gcn_w + c * 64 + d0);

    const float cP = 1.0f / 6.0f;
    const float cS = 0.23570226039551584f;   // 1/sqrt(18)
    const float c3 = 1.0f / 3.0f;
    const float cT = 0.4082482904638631f;    // 1/sqrt(6)
    const float cH = 0.5f;

    float h0[4][2];
    #pragma unroll
    for (int di = 0; di < 4; ++di) h0[di][0] = h0[di][1] = 0.f;
    #pragma unroll 1
    for (int c = 0; c < 18; ++c) {
        float wv[4];
        *(float4*)wv = *(const float4*)(&wg[c * 64 + d0]);
        const float2 xv = *(const float2*)(&xt[c * 36 + tb]);
        #pragma unroll
        for (int di = 0; di < 4; ++di) {
            h0[di][0] = fmaf(wv[di], xv.x, h0[di][0]);
            h0[di][1] = fmaf(wv[di], xv.y, h0[di][1]);
        }
    }

    float pool[4][2], star[4][2];
    #pragma unroll
    for (int di = 0; di < 4; ++di) {
        pool[di][0] = pool[di][1] = 0.f;
        star[di][0] = star[di][1] = 0.f;
    }

    #pragma unroll 1
    for (int f = 0; f < 5; ++f) {
        float hn[4][2], hprev[4][2], s12[4][2];
        #pragma unroll
        for (int n = 0; n < 4; ++n) {
            #pragma unroll
            for (int di = 0; di < 4; ++di) hn[di][0] = hn[di][1] = 0.f;
            const int cb = 18 + 10 * (4 * f + n);
            #pragma unroll
            for (int c = 0; c < 10; ++c) {
                const float2 xv = *(const float2*)(&xt[(cb + c) * 36 + tb]);
                #pragma unroll
                for (int di = 0; di < 4; ++di) {
                    hn[di][0] = fmaf(wr[c][di], xv.x, hn[di][0]);
                    hn[di][1] = fmaf(wr[c][di], xv.y, hn[di][1]);
                }
            }
            #pragma unroll
            for (int di = 0; di < 4; ++di)
                #pragma unroll
                for (int ti = 0; ti < 2; ++ti) {
                    const float h = hn[di][ti];
                    if (n == 0) {
                        star[di][ti] += h;
                        s12[di][ti] = h;
                        hprev[di][ti] = h;
                    } else if (n == 1) {
                        const float pa = fmaf(cS, h0[di][ti], c3 * (s12[di][ti] + h));
                        pool[di][ti] += fmaxf(pa, 0.f);
                        s12[di][ti] += h;
                        hprev[di][ti] = h;
                    } else if (n == 2) {
                        const float pb = c3 * (s12[di][ti] + h);
                        pool[di][ti] += fmaxf(pb, 0.f);
                        s12[di][ti] = hprev[di][ti] + h;
                        hprev[di][ti] = h;
                    } else {
                        const float pc = fmaf(cT, h, c3 * s12[di][ti]);
                        const float pe = fmaf(cT, hprev[di][ti], cH * h);
                        pool[di][ti] += fmaxf(pc, 0.f) + fmaxf(pe, 0.f);
                    }
                }
        }
    }

    float* hpb = hp + (long)b * 64 * T_LEN + t0 + tb;
    #pragma unroll
    for (int di = 0; di < 4; ++di) {
        float2 r;
        const float p0a = fmaf(cP, h0[di][0], cS * star[di][0]);
        const float p0b = fmaf(cP, h0[di][1], cS * star[di][1]);
        r.x = (pool[di][0] + fmaxf(p0a, 0.f)) * (1.0f / 21.0f);
        r.y = (pool[di][1] + fmaxf(p0b, 0.f)) * (1.0f / 21.0f);
        *(float2*)(hpb + (long)(d0 + di) * T_LEN) = r;
    }
}

// ---------------------------------------------------------------------------
// k_mstcn: one full MSTCN, fused. R11 = R10 source with ONE change:
// __launch_bounds__(128, 2).
// R10 post-mortem: VGPR_Count=92 proved the compiler coalesced winA/winB
// (a real dbuf needs ~165 live VGPRs) — it optimized for occupancy we
// can't use (grid limits us to 8 waves/CU = 2/SIMD regardless) and sank
// the loads back to just-before-use, recreating the serial
// ds_read -> waitcnt -> FMA convoy. (128,2) grants the ~256-VGPR budget
// so the named winA/winB pipeline survives codegen; zero occupancy cost.
// Falsifier: if VGPR stays ~92, theory wrong -> pivot to wave-uniform
// 512-thr + repacked-weight redesign.
// ---------------------------------------------------------------------------
template <bool FINAL>
__global__ __launch_bounds__(128, 2) void k_mstcn(
    const float* __restrict__ in,   // [B][64][T]
    const float* __restrict__ ws, const float* __restrict__ bs,
    const float* __restrict__ wm, const float* __restrict__ bm,
    const float* __restrict__ wl, const float* __restrict__ bl,
    const float* __restrict__ wo, const float* __restrict__ bo,
    float* __restrict__ out,        // [B][64][T]  (FINAL=false)
    const float* __restrict__ wd,   // [64][32]    (FINAL=true)
    const float* __restrict__ bd,   // [32]
    float* __restrict__ outp)       // [B][32]     (FINAL=true)
{
    __shared__ float smem[64 * 100]; // x-tile [c][96] stride 100; h aliased

    const int b   = blockIdx.y;
    const int t0  = blockIdx.x * 64;
    const int tid = threadIdx.x;
    const int cjg = tid >> 4;        // 0..7 composite j-group
    const int tt  = tid & 15;        // 4 t at tt*4

    // ---- stage x window [t0-32, t0+64) as [c][96], stride 100 ----
    const float* inb = in + (long)b * 64 * T_LEN;
    #pragma unroll 1
    for (int i = tid; i < 64 * 24; i += 128) {
        const int c = i / 24;
        const int q = i - c * 24;
        const int t = t0 - 32 + q * 4;
        float4 v = make_float4(0.f, 0.f, 0.f, 0.f);
        if (t >= 0) v = *(const float4*)(inb + (long)c * T_LEN + t);
        *(float4*)(&smem[c * 100 + q * 4]) = v;
    }
    __syncthreads();

    // ---- conv phase ----
    const int js = 2 * cjg;          // s channels (concat 0..15)
    const int jm = 2 * cjg;          // m channels (concat 16..31)
    const int jl = 4 * cjg;          // l channels (concat 32..63)

    float as[2][4], am[2][4], al[4][4];
    {
        const float2 b2s = *(const float2*)(bs + js);
        const float2 b2m = *(const float2*)(bm + jm);
        float b4l[4];
        *(float4*)b4l = *(const float4*)(bl + jl);
        #pragma unroll
        for (int i = 0; i < 4; ++i) {
            as[0][i] = b2s.x; as[1][i] = b2s.y;
            am[0][i] = b2m.x; am[1][i] = b2m.y;
            #pragma unroll
            for (int j = 0; j < 4; ++j) al[j][i] = b4l[j];
        }
    }

    float2 wsr[3], wmr[5];
    float  wlr[9][4];
    #pragma unroll
    for (int k = 0; k < 3; ++k) wsr[k] = *(const float2*)(ws + (k * 64) * 16 + js);
    #pragma unroll
    for (int k = 0; k < 5; ++k) wmr[k] = *(const float2*)(wm + (k * 64) * 16 + jm);
    #pragma unroll
    for (int k = 0; k < 9; ++k) *(float4*)wlr[k] = *(const float4*)(wl + (k * 64) * 32 + jl);

    // window double buffer: winA holds current c, winB prefetches c+1
    float winA[36], winB[36];

#define LOADWIN(W, CC) do {                                              \
        const float* rb_ = &smem[(CC) * 100 + tt * 4];                   \
        _Pragma("unroll")                                                \
        for (int m_ = 0; m_ < 9; ++m_)                                   \
            *(float4*)(&(W)[4 * m_]) = *(const float4*)(rb_ + 4 * m_);   \
    } while (0)

#define COMPUTE(W, C) do {                                               \
        const int cn_ = ((C) < 63) ? (C) + 1 : 63;                       \
        _Pragma("unroll")                                                \
        for (int k = 0; k < 3; ++k) {                                    \
            _Pragma("unroll")                                            \
            for (int i = 0; i < 4; ++i) {                                \
                const float v = (W)[30 + i + k];                         \
                as[0][i] = fmaf(wsr[k].x, v, as[0][i]);                  \
                as[1][i] = fmaf(wsr[k].y, v, as[1][i]);                  \
            }                                                            \
            wsr[k] = *(const float2*)(ws + (k * 64 + cn_) * 16 + js);    \
        }                                                                \
        _Pragma("unroll")                                                \
        for (int k = 0; k < 5; ++k) {                                    \
            _Pragma("unroll")                                            \
            for (int i = 0; i < 4; ++i) {                                \
                const float v = (W)[24 + i + 2 * k];                     \
                am[0][i] = fmaf(wmr[k].x, v, am[0][i]);                  \
                am[1][i] = fmaf(wmr[k].y, v, am[1][i]);                  \
            }                                                            \
            wmr[k] = *(const float2*)(wm + (k * 64 + cn_) * 16 + jm);    \
        }                                                                \
        _Pragma("unroll")                                                \
        for (int k = 0; k < 9; ++k) {                                    \
            _Pragma("unroll")                                            \
            for (int i = 0; i < 4; ++i) {                                \
                const float v = (W)[i + 4 * k];                          \
                al[0][i] = fmaf(wlr[k][0], v, al[0][i]);                 \
                al[1][i] = fmaf(wlr[k][1], v, al[1][i]);                 \
                al[2][i] = fmaf(wlr[k][2], v, al[2][i]);                 \
                al[3][i] = fmaf(wlr[k][3], v, al[3][i]);                 \
            }                                                            \
            *(float4*)wlr[k] = *(const float4*)(wl + (k * 64 + cn_) * 32 + jl); \
        }                                                                \
    } while (0)

    LOADWIN(winA, 0);
    #pragma unroll 1
    for (int c = 0; c < 64; c += 2) {
        // prefetch window c+1 into winB, then compute c from winA
        LOADWIN(winB, c + 1);
        COMPUTE(winA, c);
        // prefetch window c+2 into winA (clamped dummy on last iter)
        LOADWIN(winA, (c + 2 < 64) ? c + 2 : 63);
        COMPUTE(winB, c + 1);
    }

#undef LOADWIN
#undef COMPUTE

    // ---- relu + stage h [64 j][64 t] stride 68 (aliased) ----
    __syncthreads();
    #pragma unroll
    for (int j = 0; j < 2; ++j)
        *(float4*)(&smem[(js + j) * 68 + tt * 4]) =
            make_float4(fmaxf(as[j][0], 0.f), fmaxf(as[j][1], 0.f),
                        fmaxf(as[j][2], 0.f), fmaxf(as[j][3], 0.f));
    #pragma unroll
    for (int j = 0; j < 2; ++j)
        *(float4*)(&smem[(16 + jm + j) * 68 + tt * 4]) =
            make_float4(fmaxf(am[j][0], 0.f), fmaxf(am[j][1], 0.f),
                        fmaxf(am[j][2], 0.f), fmaxf(am[j][3], 0.f));
    #pragma unroll
    for (int j = 0; j < 4; ++j)
        *(float4*)(&smem[(32 + jl + j) * 68 + tt * 4]) =
            make_float4(fmaxf(al[j][0], 0.f), fmaxf(al[j][1], 0.f),
                        fmaxf(al[j][2], 0.f), fmaxf(al[j][3], 0.f));
    __syncthreads();

    // ---- conv_out 64->64 (no relu): thread = 8 d x 4 t ----
    const int d0 = cjg * 8;
    float o[8][4];
    {
        float bv[8];
        *(float4*)(&bv[0]) = *(const float4*)(bo + d0);
        *(float4*)(&bv[4]) = *(const float4*)(bo + d0 + 4);
        #pragma unroll
        for (int di = 0; di < 8; ++di)
            #pragma unroll
            for (int i = 0; i < 4; ++i) o[di][i] = bv[di];
    }
    #pragma unroll 4
    for (int j = 0; j < 64; ++j) {
        float wv[8], hv[4];
        *(float4*)(&wv[0]) = *(const float4*)(wo + j * 64 + d0);
        *(float4*)(&wv[4]) = *(const float4*)(wo + j * 64 + d0 + 4);
        *(float4*)hv       = *(const float4*)(&smem[j * 68 + tt * 4]);
        #pragma unroll
        for (int di = 0; di < 8; ++di)
            #pragma unroll
            for (int i = 0; i < 4; ++i)
                o[di][i] = fmaf(wv[di], hv[i], o[di][i]);
    }

    if (!FINAL) {
        float* ob = out + (long)b * 64 * T_LEN + t0 + tt * 4;
        #pragma unroll
        for (int di = 0; di < 8; ++di)
            *(float4*)(ob + (long)(d0 + di) * T_LEN) =
                make_float4(o[di][0], o[di][1], o[di][2], o[di][3]);
    } else {
        // ---- stage t2 [64 d][64 t], then dense 64->32 + tanh + mean ----
        __syncthreads();
        #pragma unroll
        for (int di = 0; di < 8; ++di)
            *(float4*)(&smem[(d0 + di) * 68 + tt * 4]) =
                make_float4(o[di][0], o[di][1], o[di][2], o[di][3]);
        __syncthreads();

        const int eg = tid >> 5;       // 4 groups x 8 e
        const int e0 = eg * 8;
        const int tl = tid & 31;       // 2 t at tl*2
        float fa[8], fb[8];
        *(float4*)(&fa[0]) = *(const float4*)(bd + e0);
        *(float4*)(&fa[4]) = *(const float4*)(bd + e0 + 4);
        #pragma unroll
        for (int e = 0; e < 8; ++e) fb[e] = fa[e];

        #pragma unroll 4
        for (int d = 0; d < 64; ++d) {
            const float2 hv = *(const float2*)(&smem[d * 68 + tl * 2]);
            float wv[8];
            *(float4*)(&wv[0]) = *(const float4*)(wd + d * 32 + e0);
            *(float4*)(&wv[4]) = *(const float4*)(wd + d * 32 + e0 + 4);
            #pragma unroll
            for (int e = 0; e < 8; ++e) {
                fa[e] = fmaf(wv[e], hv.x, fa[e]);
                fb[e] = fmaf(wv[e], hv.y, fb[e]);
            }
        }
        #pragma unroll
        for (int e = 0; e < 8; ++e) {
            float v = (tanhf(fa[e]) + tanhf(fb[e])) * (1.0f / (float)T_LEN);
            v += __shfl_down(v, 16, 32);
            v += __shfl_down(v, 8, 32);
            v += __shfl_down(v, 4, 32);
            v += __shfl_down(v, 2, 32);
            v += __shfl_down(v, 1, 32);
            if (tl == 0) atomicAdd(&outp[b * 32 + e0 + e], v);
        }
    }
}

extern "C" void kernel_launch(void* const* d_in, const int* in_sizes, int n_in,
                              void* d_out, int out_size, void* d_ws, size_t ws_size,
                              hipStream_t stream) {
    const float* x     = (const float*)d_in[0];
    const float* gcn_w = (const float*)d_in[1];
    const float* wd    = (const float*)d_in[2];
    const float* bd    = (const float*)d_in[3];
    const float* t1_ws = (const float*)d_in[4];
    const float* t1_bs = (const float*)d_in[5];
    const float* t1_wm = (const float*)d_in[6];
    const float* t1_bm = (const float*)d_in[7];
    const float* t1_wl = (const float*)d_in[8];
    const float* t1_bl = (const float*)d_in[9];
    const float* t1_wo = (const float*)d_in[10];
    const float* t1_bo = (const float*)d_in[11];
    const float* t2_ws = (const float*)d_in[12];
    const float* t2_bs = (const float*)d_in[13];
    const float* t2_wm = (const float*)d_in[14];
    const float* t2_bm = (const float*)d_in[15];
    const float* t2_wl = (const float*)d_in[16];
    const float* t2_bl = (const float*)d_in[17];
    const float* t2_wo = (const float*)d_in[18];
    const float* t2_bo = (const float*)d_in[19];

    float* b0 = (float*)d_ws;                          // [16][64][4096]
    float* b1 = b0 + (size_t)BATCH * 64 * T_LEN;       // [16][64][4096]

    hipMemsetAsync(d_out, 0, (size_t)out_size * sizeof(float), stream);

    k_gcn<<<dim3(T_LEN / 32, BATCH), 256, 0, stream>>>(x, gcn_w, b0);

    k_mstcn<false><<<dim3(T_LEN / 64, BATCH), 128, 0, stream>>>(
        b0, t1_ws, t1_bs, t1_wm, t1_bm, t1_wl, t1_bl, t1_wo, t1_bo,
        b1, nullptr, nullptr, nullptr);

    k_mstcn<true><<<dim3(T_LEN / 64, BATCH), 128, 0, stream>>>(
        b1, t2_ws, t2_bs, t2_wm, t2_bm, t2_wl, t2_bl, t2_wo, t2_bo,
        nullptr, wd, bd, (float*)d_out);
}